// Round 5
// baseline (500.019 us; speedup 1.0000x reference)
//
#include <hip/hip_runtime.h>
#include <cstdint>
#include <cstddef>

// Problem sizes (fixed by the reference)
#define MDIM 16384   // N_INPUT
#define CDIM 4096    // NUM_CENTERS
#define DDIM 256     // DIM
#define KDIM 512     // folded K (elements == fp8 bytes)

typedef float f32x4  __attribute__((ext_vector_type(4)));
typedef int   i32x4v __attribute__((ext_vector_type(4)));
typedef int   i32x8v __attribute__((ext_vector_type(8)));

// ---------------------------------------------------------------------------
// Fused prep (fp8 e4m3 via HW packed cvt):
//  blocks [0,4096):    A'[n][d] = x, A'[n][256+d] = x^2 ; zero score+done
//  blocks [4096,5120): inv = 1/(2 s^2); B'[c][d] = -2*c*inv; B'[c][256+d]=inv
//                      constc[c] = sum_d c^2*inv (fp32, one wave per center)
// ---------------------------------------------------------------------------
__global__ __launch_bounds__(256) void prep(
    const float* __restrict__ x, const float* __restrict__ centers,
    const float* __restrict__ sigmas,
    unsigned char* __restrict__ Ap, unsigned char* __restrict__ Bp,
    float* __restrict__ constc, float* __restrict__ score,
    unsigned* __restrict__ done) {
    int b = blockIdx.x, tid = threadIdx.x;
    if (b < 4096) {
        int idx4 = b * 256 + tid;                 // over MDIM*DDIM/4
        float4 v = ((const float4*)x)[idx4];
        int n = idx4 >> 6, dq = idx4 & 63;
        int p0 = __builtin_amdgcn_cvt_pk_fp8_f32(v.x, v.y, 0, false);
        p0     = __builtin_amdgcn_cvt_pk_fp8_f32(v.z, v.w, p0, true);
        int p1 = __builtin_amdgcn_cvt_pk_fp8_f32(v.x * v.x, v.y * v.y, 0, false);
        p1     = __builtin_amdgcn_cvt_pk_fp8_f32(v.z * v.z, v.w * v.w, p1, true);
        *(int*)(Ap + (size_t)n * KDIM + dq * 4)        = p0;
        *(int*)(Ap + (size_t)n * KDIM + DDIM + dq * 4) = p1;
        if (idx4 < MDIM) score[idx4] = 0.0f;
        if (idx4 < MDIM / 128) done[idx4] = 0u;
    } else {
        int gid = (b - 4096) * 256 + tid;         // over CDIM*DDIM/4
        int c = gid >> 6, q = gid & 63;
        float4 cv = ((const float4*)centers)[gid];
        float4 sv = ((const float4*)sigmas)[gid];
        float ix = 1.0f / (2.0f * sv.x * sv.x);
        float iy = 1.0f / (2.0f * sv.y * sv.y);
        float iz = 1.0f / (2.0f * sv.z * sv.z);
        float iw = 1.0f / (2.0f * sv.w * sv.w);
        int p0 = __builtin_amdgcn_cvt_pk_fp8_f32(-2.0f * cv.x * ix, -2.0f * cv.y * iy, 0, false);
        p0     = __builtin_amdgcn_cvt_pk_fp8_f32(-2.0f * cv.z * iz, -2.0f * cv.w * iw, p0, true);
        int p1 = __builtin_amdgcn_cvt_pk_fp8_f32(ix, iy, 0, false);
        p1     = __builtin_amdgcn_cvt_pk_fp8_f32(iz, iw, p1, true);
        *(int*)(Bp + (size_t)c * KDIM + q * 4)        = p0;
        *(int*)(Bp + (size_t)c * KDIM + DDIM + q * 4) = p1;
        float t = cv.x * cv.x * ix + cv.y * cv.y * iy
                + cv.z * cv.z * iz + cv.w * cv.w * iw;
        #pragma unroll
        for (int m = 32; m; m >>= 1) t += __shfl_down(t, m, 64);
        if ((tid & 63) == 0) constc[c] = t;       // one wave == one center
    }
}

// ---------------------------------------------------------------------------
// Fused MX-fp8 GEMM + exp + weighted C-reduction + (last-block) sigmoid.
// d2 = A' B'^T + constc ; score[m] += sum_n exp(-d2[m][n]) * w[n]
// 128x128 tile, BK=256 (2 barrier rounds instead of 4 — halves drain
// exposure), 4 waves, 4x4 16x16x128 mfma_scale/wave, unit E8M0 scales.
// XOR swizzle within each 128-B half-row: chunk c of row r lives at slot
// ((c&7)^(r&7)) | (c&8)  -> 2-way-aliased fragment reads (free).
// launch_bounds(256,2): 256-reg budget, spill impossible; LDS 64 KB -> 2
// blocks/CU (matches R3's measured ~2.2 effective residency).
// ---------------------------------------------------------------------------
__global__ __launch_bounds__(256, 2) void gemm_fused(
    const unsigned char* __restrict__ A, const unsigned char* __restrict__ B,
    const float* __restrict__ constc, const float* __restrict__ w,
    const float* __restrict__ blin,
    float* __restrict__ score, unsigned* __restrict__ done,
    float* __restrict__ out) {

    __shared__ unsigned char As[128 * 256];   // 32 KB
    __shared__ unsigned char Bs[128 * 256];   // 32 KB  (total = 64 KB exactly)

    const int tid  = threadIdx.x;
    const int wave = tid >> 6;
    const int lane = tid & 63;
    const int quad = lane >> 4;      // 0..3
    const int l16  = lane & 15;

    const int bm = blockIdx.y;       // 0..127  (M blocks)
    const int bn = blockIdx.x;       // 0..31   (C blocks)

    const int wave_m = (wave & 1) * 64;
    const int wave_n = (wave >> 1) * 64;

    f32x4 acc[4][4] = {};

    // staging: one global_load_lds(16B) per lane covers 1024 B = 4 rows x 256 B.
    // lane -> (row-in-slab = lane>>4, slot = lane&15). Fetch the XOR-swizzled
    // global chunk so LDS slot s of row r holds chunk ((s&7)^(r&7))|(s&8).
    const int srow = lane >> 4;      // 0..3
    const int slot = lane & 15;      // 0..15 (16B units)

    const unsigned char* Abase = A + (size_t)(bm * 128) * KDIM;
    const unsigned char* Bbase = B + (size_t)(bn * 128) * KDIM;

    const int rsw = l16 & 7;

    for (int k0 = 0; k0 < KDIM; k0 += 256) {
        #pragma unroll
        for (int c = 0; c < 8; ++c) {
            int slab = wave * 8 + c;               // 0..31 (4-row slabs)
            int row  = slab * 4 + srow;            // 0..127
            int g    = ((slot & 7) ^ (row & 7)) | (slot & 8);
            const unsigned char* ga = Abase + (size_t)row * KDIM + k0 + g * 16;
            const unsigned char* gb = Bbase + (size_t)row * KDIM + k0 + g * 16;
            __builtin_amdgcn_global_load_lds(
                (const __attribute__((address_space(1))) void*)ga,
                (__attribute__((address_space(3))) void*)(As + slab * 1024), 16, 0, 0);
            __builtin_amdgcn_global_load_lds(
                (const __attribute__((address_space(1))) void*)gb,
                (__attribute__((address_space(3))) void*)(Bs + slab * 1024), 16, 0, 0);
        }
        __syncthreads();

        #pragma unroll
        for (int kk = 0; kk < 256; kk += 128) {
            const int cb  = (kk >> 4) & 8;                       // chunk-half bit
            const int so0 = (((2 * quad)     ^ rsw) | cb) * 16;  // swizzled slots
            const int so1 = (((2 * quad + 1) ^ rsw) | cb) * 16;

            i32x8v af[4];
            #pragma unroll
            for (int i = 0; i < 4; ++i) {
                const unsigned char* pa = As + (wave_m + i * 16 + l16) * 256;
                i32x4v* h = (i32x4v*)&af[i];
                h[0] = *(const i32x4v*)(pa + so0);
                h[1] = *(const i32x4v*)(pa + so1);
            }
            #pragma unroll
            for (int j = 0; j < 4; ++j) {
                const unsigned char* pb = Bs + (wave_n + j * 16 + l16) * 256;
                i32x8v bf;
                i32x4v* h = (i32x4v*)&bf;
                h[0] = *(const i32x4v*)(pb + so0);
                h[1] = *(const i32x4v*)(pb + so1);
                #pragma unroll
                for (int i = 0; i < 4; ++i)
                    acc[i][j] = __builtin_amdgcn_mfma_scale_f32_16x16x128_f8f6f4(
                        af[i], bf, acc[i][j],
                        0 /*cbsz: fp8 e4m3*/, 0 /*blgp: fp8 e4m3*/,
                        0, 0x7F7F7F7F /*scale A = 1.0*/,
                        0, 0x7F7F7F7F /*scale B = 1.0*/);
            }
        }
        __syncthreads();
    }

    // Epilogue: d2 -> exp -> *w -> reduce over this tile's 128 columns.
    // C/D layout (16x16 shapes): col = l16 (=n), row = quad*4 + reg (=m).
    const int n0 = bn * 128 + wave_n + l16;
    float rowsum[4][4];
    #pragma unroll
    for (int i = 0; i < 4; ++i)
        #pragma unroll
        for (int r = 0; r < 4; ++r) rowsum[i][r] = 0.0f;

    const float NEG_LOG2E = -1.4426950408889634f;
    #pragma unroll
    for (int j = 0; j < 4; ++j) {
        int ng = n0 + j * 16;
        float wj = w[ng];
        float cj = constc[ng];
        #pragma unroll
        for (int i = 0; i < 4; ++i)
            #pragma unroll
            for (int r = 0; r < 4; ++r) {
                float d2 = acc[i][j][r] + cj;
                rowsum[i][r] += exp2f(NEG_LOG2E * d2) * wj;
            }
    }

    #pragma unroll
    for (int mask = 1; mask < 16; mask <<= 1)
        #pragma unroll
        for (int i = 0; i < 4; ++i)
            #pragma unroll
            for (int r = 0; r < 4; ++r)
                rowsum[i][r] += __shfl_xor(rowsum[i][r], mask, 64);

    if (l16 == 0) {
        #pragma unroll
        for (int i = 0; i < 4; ++i)
            #pragma unroll
            for (int r = 0; r < 4; ++r) {
                int mg = bm * 128 + wave_m + i * 16 + quad * 4 + r;
                atomicAdd(&score[mg], rowsum[i][r]);
            }
    }

    // ---- fused finalize: last bn-block for this bm applies sigmoid ----
    __threadfence();                      // release: score adds visible
    unsigned* lf = (unsigned*)As;         // reuse LDS (all reads done)
    if (tid == 0) {
        unsigned old = atomicAdd(&done[bm], 1u);
        *lf = (old == 31u) ? 1u : 0u;
    }
    __syncthreads();
    if (*lf) {
        __threadfence();                  // acquire
        if (tid < 128) {
            int mg = bm * 128 + tid;
            float s = atomicAdd(&score[mg], 0.0f) + blin[0];  // coherent read
            out[mg] = 1.0f / (1.0f + exp2f(-1.4426950408889634f * s));
        }
    }
}

extern "C" void kernel_launch(void* const* d_in, const int* in_sizes, int n_in,
                              void* d_out, int out_size, void* d_ws, size_t ws_size,
                              hipStream_t stream) {
    const float* x       = (const float*)d_in[0];
    const float* centers = (const float*)d_in[1];
    const float* sigmas  = (const float*)d_in[2];
    const float* w_lin   = (const float*)d_in[3];
    const float* b_lin   = (const float*)d_in[4];
    float* out = (float*)d_out;

    char* ws = (char*)d_ws;
    unsigned char* Ap = (unsigned char*)ws;                         // 8 MB
    unsigned char* Bp = (unsigned char*)(ws + (size_t)MDIM * KDIM); // 2 MB
    float* cc    = (float*)(ws + (size_t)MDIM * KDIM + (size_t)CDIM * KDIM); // 16 KB
    float* score = (float*)((char*)cc + CDIM * sizeof(float));      // 64 KB
    unsigned* done = (unsigned*)((char*)score + MDIM * sizeof(float)); // 512 B

    prep<<<dim3(4096 + 1024), dim3(256), 0, stream>>>(
        x, centers, sigmas, Ap, Bp, cc, score, done);
    gemm_fused<<<dim3(CDIM / 128, MDIM / 128), dim3(256), 0, stream>>>(
        Ap, Bp, cc, w_lin, b_lin, score, done, out);
}

// Round 6
// 134.743 us; speedup vs baseline: 3.7109x; 3.7109x over previous
//
#include <hip/hip_runtime.h>
#include <cstdint>
#include <cstddef>

// Problem sizes (fixed by the reference)
#define MDIM 16384   // N_INPUT
#define CDIM 4096    // NUM_CENTERS
#define DDIM 256     // DIM
#define KDIM 512     // folded K (elements == fp8 bytes)

typedef float f32x4  __attribute__((ext_vector_type(4)));
typedef int   i32x4v __attribute__((ext_vector_type(4)));
typedef int   i32x8v __attribute__((ext_vector_type(8)));

// ---------------------------------------------------------------------------
// Fused prep (fp8 e4m3 via HW packed cvt):
//  blocks [0,4096):    A'[n][d] = x, A'[n][256+d] = x^2 ; zero score
//  blocks [4096,5120): inv = 1/(2 s^2); B'[c][d] = -2*c*inv; B'[c][256+d]=inv
//                      constc[c] = sum_d c^2*inv (fp32, one wave per center)
// ---------------------------------------------------------------------------
__global__ __launch_bounds__(256) void prep(
    const float* __restrict__ x, const float* __restrict__ centers,
    const float* __restrict__ sigmas,
    unsigned char* __restrict__ Ap, unsigned char* __restrict__ Bp,
    float* __restrict__ constc, float* __restrict__ score) {
    int b = blockIdx.x, tid = threadIdx.x;
    if (b < 4096) {
        int idx4 = b * 256 + tid;                 // over MDIM*DDIM/4
        float4 v = ((const float4*)x)[idx4];
        int n = idx4 >> 6, dq = idx4 & 63;
        int p0 = __builtin_amdgcn_cvt_pk_fp8_f32(v.x, v.y, 0, false);
        p0     = __builtin_amdgcn_cvt_pk_fp8_f32(v.z, v.w, p0, true);
        int p1 = __builtin_amdgcn_cvt_pk_fp8_f32(v.x * v.x, v.y * v.y, 0, false);
        p1     = __builtin_amdgcn_cvt_pk_fp8_f32(v.z * v.z, v.w * v.w, p1, true);
        *(int*)(Ap + (size_t)n * KDIM + dq * 4)        = p0;
        *(int*)(Ap + (size_t)n * KDIM + DDIM + dq * 4) = p1;
        if (idx4 < MDIM) score[idx4] = 0.0f;
    } else {
        int gid = (b - 4096) * 256 + tid;         // over CDIM*DDIM/4
        int c = gid >> 6, q = gid & 63;
        float4 cv = ((const float4*)centers)[gid];
        float4 sv = ((const float4*)sigmas)[gid];
        float ix = 1.0f / (2.0f * sv.x * sv.x);
        float iy = 1.0f / (2.0f * sv.y * sv.y);
        float iz = 1.0f / (2.0f * sv.z * sv.z);
        float iw = 1.0f / (2.0f * sv.w * sv.w);
        int p0 = __builtin_amdgcn_cvt_pk_fp8_f32(-2.0f * cv.x * ix, -2.0f * cv.y * iy, 0, false);
        p0     = __builtin_amdgcn_cvt_pk_fp8_f32(-2.0f * cv.z * iz, -2.0f * cv.w * iw, p0, true);
        int p1 = __builtin_amdgcn_cvt_pk_fp8_f32(ix, iy, 0, false);
        p1     = __builtin_amdgcn_cvt_pk_fp8_f32(iz, iw, p1, true);
        *(int*)(Bp + (size_t)c * KDIM + q * 4)        = p0;
        *(int*)(Bp + (size_t)c * KDIM + DDIM + q * 4) = p1;
        float t = cv.x * cv.x * ix + cv.y * cv.y * iy
                + cv.z * cv.z * iz + cv.w * cv.w * iw;
        #pragma unroll
        for (int m = 32; m; m >>= 1) t += __shfl_down(t, m, 64);
        if ((tid & 63) == 0) constc[c] = t;       // one wave == one center
    }
}

// ---------------------------------------------------------------------------
// Fused MX-fp8 GEMM + exp + weighted C-reduction.
// d2 = A' B'^T + constc ; score[m] += sum_n exp(-d2[m][n]) * w[n]
// R5: 256x128 tile (M x N), BK=128 bytes. 4 waves, each wave owns 64 M-rows
// x 128 N-cols: acc 4x8 f32x4 (128 regs), af[4] long-lived, bf per-j.
// 16x16x128 mfma_scale, unit E8M0 scales. XOR swizzle (R3-proven): 16B chunk
// g of row r at slot g^(r&7). LDS 48 KB -> 2 blocks/CU; (256,2) -> 256-reg
// unified budget, live ~200, no spill. Separate finalize (R4 fence lesson).
// ---------------------------------------------------------------------------
__global__ __launch_bounds__(256, 2) void gemm_fused(
    const unsigned char* __restrict__ A, const unsigned char* __restrict__ B,
    const float* __restrict__ constc, const float* __restrict__ w,
    float* __restrict__ score) {

    __shared__ unsigned char As[256 * 128];   // 32 KB
    __shared__ unsigned char Bs[128 * 128];   // 16 KB

    const int tid  = threadIdx.x;
    const int wave = tid >> 6;
    const int lane = tid & 63;
    const int quad = lane >> 4;      // 0..3
    const int l16  = lane & 15;

    const int bm = blockIdx.y;       // 0..63   (M blocks of 256)
    const int bn = blockIdx.x;       // 0..31   (C blocks of 128)

    const int wave_m = wave * 64;    // wave's 64 M-rows

    f32x4 acc[4][8] = {};

    // staging: one global_load_lds(16B)/lane stages 1024 B = 8 rows x 128 B.
    // lane -> row (lane>>3), slot (lane&7); fetch XOR-swizzled global chunk.
    const int st_row = lane >> 3;                     // 0..7
    const int st_k   = ((lane & 7) ^ st_row) * 16;    // swizzled global byte off

    const unsigned char* Abase = A + (size_t)(bm * 256) * KDIM;
    const unsigned char* Bbase = B + (size_t)(bn * 128) * KDIM;

    // fragment read slots: lane (l16,quad) needs 16B chunks 2q, 2q+1 of its
    // row, each at XOR-swizzled slot (c ^ (l16&7)).
    const int rsw = l16 & 7;
    const int s0  = ((2 * quad)     ^ rsw) * 16;
    const int s1  = ((2 * quad + 1) ^ rsw) * 16;

    for (int k0 = 0; k0 < KDIM; k0 += 128) {
        #pragma unroll
        for (int c = 0; c < 8; ++c) {             // A: 32 slabs of 8 rows
            int slab = wave * 8 + c;              // 0..31
            const unsigned char* ga = Abase + (size_t)(slab * 8 + st_row) * KDIM + k0 + st_k;
            __builtin_amdgcn_global_load_lds(
                (const __attribute__((address_space(1))) void*)ga,
                (__attribute__((address_space(3))) void*)(As + slab * 1024), 16, 0, 0);
        }
        #pragma unroll
        for (int c = 0; c < 4; ++c) {             // B: 16 slabs of 8 rows
            int slab = wave * 4 + c;              // 0..15
            const unsigned char* gb = Bbase + (size_t)(slab * 8 + st_row) * KDIM + k0 + st_k;
            __builtin_amdgcn_global_load_lds(
                (const __attribute__((address_space(1))) void*)gb,
                (__attribute__((address_space(3))) void*)(Bs + slab * 1024), 16, 0, 0);
        }
        __syncthreads();

        i32x8v af[4];
        #pragma unroll
        for (int i = 0; i < 4; ++i) {
            const unsigned char* pa = As + (wave_m + i * 16 + l16) * 128;
            i32x4v* h = (i32x4v*)&af[i];
            h[0] = *(const i32x4v*)(pa + s0);
            h[1] = *(const i32x4v*)(pa + s1);
        }
        #pragma unroll
        for (int j = 0; j < 8; ++j) {
            const unsigned char* pb = Bs + (j * 16 + l16) * 128;
            i32x8v bf;
            i32x4v* h = (i32x4v*)&bf;
            h[0] = *(const i32x4v*)(pb + s0);
            h[1] = *(const i32x4v*)(pb + s1);
            #pragma unroll
            for (int i = 0; i < 4; ++i)
                acc[i][j] = __builtin_amdgcn_mfma_scale_f32_16x16x128_f8f6f4(
                    af[i], bf, acc[i][j],
                    0 /*cbsz: fp8 e4m3*/, 0 /*blgp: fp8 e4m3*/,
                    0, 0x7F7F7F7F /*scale A = 1.0*/,
                    0, 0x7F7F7F7F /*scale B = 1.0*/);
        }
        __syncthreads();
    }

    // Epilogue: d2 -> exp -> *w -> reduce over this tile's 128 columns.
    // C/D layout (16x16 shapes): col = l16 (=n), row = quad*4 + reg (=m).
    float rowsum[4][4];
    #pragma unroll
    for (int i = 0; i < 4; ++i)
        #pragma unroll
        for (int r = 0; r < 4; ++r) rowsum[i][r] = 0.0f;

    const float NEG_LOG2E = -1.4426950408889634f;
    #pragma unroll
    for (int j = 0; j < 8; ++j) {
        int ng = bn * 128 + j * 16 + l16;
        float wj = w[ng];
        float cj = constc[ng];
        #pragma unroll
        for (int i = 0; i < 4; ++i)
            #pragma unroll
            for (int r = 0; r < 4; ++r) {
                float d2 = acc[i][j][r] + cj;
                rowsum[i][r] += exp2f(NEG_LOG2E * d2) * wj;
            }
    }

    #pragma unroll
    for (int mask = 1; mask < 16; mask <<= 1)
        #pragma unroll
        for (int i = 0; i < 4; ++i)
            #pragma unroll
            for (int r = 0; r < 4; ++r)
                rowsum[i][r] += __shfl_xor(rowsum[i][r], mask, 64);

    if (l16 == 0) {
        #pragma unroll
        for (int i = 0; i < 4; ++i)
            #pragma unroll
            for (int r = 0; r < 4; ++r) {
                int mg = bm * 256 + wave_m + i * 16 + quad * 4 + r;
                atomicAdd(&score[mg], rowsum[i][r]);
            }
    }
}

// ---------------------------------------------------------------------------
// finalize: out[n] = sigmoid(score[n] + b)
// ---------------------------------------------------------------------------
__global__ void finalize(const float* __restrict__ score,
                         const float* __restrict__ b,
                         float* __restrict__ out) {
    int n = blockIdx.x * 256 + threadIdx.x;
    if (n < MDIM) {
        float s = score[n] + b[0];
        out[n] = 1.0f / (1.0f + exp2f(-1.4426950408889634f * s));
    }
}

extern "C" void kernel_launch(void* const* d_in, const int* in_sizes, int n_in,
                              void* d_out, int out_size, void* d_ws, size_t ws_size,
                              hipStream_t stream) {
    const float* x       = (const float*)d_in[0];
    const float* centers = (const float*)d_in[1];
    const float* sigmas  = (const float*)d_in[2];
    const float* w_lin   = (const float*)d_in[3];
    const float* b_lin   = (const float*)d_in[4];
    float* out = (float*)d_out;

    char* ws = (char*)d_ws;
    unsigned char* Ap = (unsigned char*)ws;                         // 8 MB
    unsigned char* Bp = (unsigned char*)(ws + (size_t)MDIM * KDIM); // 2 MB
    float* cc    = (float*)(ws + (size_t)MDIM * KDIM + (size_t)CDIM * KDIM); // 16 KB
    float* score = (float*)((char*)cc + CDIM * sizeof(float));      // 64 KB

    prep<<<dim3(4096 + 1024), dim3(256), 0, stream>>>(
        x, centers, sigmas, Ap, Bp, cc, score);
    gemm_fused<<<dim3(CDIM / 128, MDIM / 256), dim3(256), 0, stream>>>(
        Ap, Bp, cc, w_lin, score);
    finalize<<<dim3((MDIM + 255) / 256), dim3(256), 0, stream>>>(score, b_lin, out);
}